// Round 3
// baseline (103.456 us; speedup 1.0000x reference)
//
#include <hip/hip_runtime.h>

// Voxelizer: splat N gaussians into a D*H*W f32 volume.
// center = (pos+1)*0.5*dim - 0.5 ; base voxel = rint(center) (round-half-even,
// matching jnp.round); 5x5x5 neighborhood; mahal = |diag(1/s) R^T d|^2 with
// d = (voxel - center)/(dim/2); add exp(-0.5*mahal)*density where in-bounds
// and mahal<=9.

#define VOX_D 128
#define VOX_H 128
#define VOX_W 128
#define MAX_R 2

__global__ __launch_bounds__(256) void voxelize_splat(
    const float* __restrict__ positions,  // (N,3)
    const float* __restrict__ scales,     // (N,3)
    const float* __restrict__ rotations,  // (N,4) w,x,y,z
    const float* __restrict__ density,    // (N,)
    float* __restrict__ volume,           // (D*H*W,)
    int n)
{
    int i = blockIdx.x * blockDim.x + threadIdx.x;
    if (i >= n) return;

    const float p0 = positions[3 * i + 0];
    const float p1 = positions[3 * i + 1];
    const float p2 = positions[3 * i + 2];

    // voxel-space center (all dims are 128)
    const float c0 = (p0 + 1.0f) * 64.0f - 0.5f;
    const float c1 = (p1 + 1.0f) * 64.0f - 0.5f;
    const float c2 = (p2 + 1.0f) * 64.0f - 0.5f;

    // quaternion -> rotation matrix (normalized)
    float qw = rotations[4 * i + 0];
    float qx = rotations[4 * i + 1];
    float qy = rotations[4 * i + 2];
    float qz = rotations[4 * i + 3];
    const float qn = rsqrtf(qw * qw + qx * qx + qy * qy + qz * qz);
    qw *= qn; qx *= qn; qy *= qn; qz *= qn;

    const float r00 = 1.0f - 2.0f * (qy * qy + qz * qz);
    const float r01 = 2.0f * (qx * qy - qw * qz);
    const float r02 = 2.0f * (qx * qz + qw * qy);
    const float r10 = 2.0f * (qx * qy + qw * qz);
    const float r11 = 1.0f - 2.0f * (qx * qx + qz * qz);
    const float r12 = 2.0f * (qy * qz - qw * qx);
    const float r20 = 2.0f * (qx * qz - qw * qy);
    const float r21 = 2.0f * (qy * qz + qw * qx);
    const float r22 = 1.0f - 2.0f * (qx * qx + qy * qy);

    const float si0 = 1.0f / (scales[3 * i + 0] + 1e-8f);
    const float si1 = 1.0f / (scales[3 * i + 1] + 1e-8f);
    const float si2 = 1.0f / (scales[3 * i + 2] + 1e-8f);

    const float dens = density[i];

    // base integer voxel (round half to even, matches jnp.round)
    const int b0 = (int)rintf(c0);
    const int b1 = (int)rintf(c1);
    const int b2 = (int)rintf(c2);

    const float inv_half = 1.0f / 64.0f;

    // Precompute per-axis normalized offsets and validity
    float d0v[2 * MAX_R + 1], d1v[2 * MAX_R + 1], d2v[2 * MAX_R + 1];
    bool v0v[2 * MAX_R + 1], v1v[2 * MAX_R + 1], v2v[2 * MAX_R + 1];
#pragma unroll
    for (int k = -MAX_R; k <= MAX_R; ++k) {
        const int t = k + MAX_R;
        d0v[t] = ((float)(b0 + k) - c0) * inv_half;
        d1v[t] = ((float)(b1 + k) - c1) * inv_half;
        d2v[t] = ((float)(b2 + k) - c2) * inv_half;
        v0v[t] = (b0 + k >= 0) && (b0 + k < VOX_D);
        v1v[t] = (b1 + k >= 0) && (b1 + k < VOX_H);
        v2v[t] = (b2 + k >= 0) && (b2 + k < VOX_W);
    }

#pragma unroll
    for (int t0 = 0; t0 < 2 * MAX_R + 1; ++t0) {
        const float d0 = d0v[t0];
        // partial column dots: (R^T d) with only d0 term
        const float a0 = r00 * d0;
        const float a1 = r01 * d0;
        const float a2 = r02 * d0;
        const int g0 = b0 + t0 - MAX_R;
#pragma unroll
        for (int t1 = 0; t1 < 2 * MAX_R + 1; ++t1) {
            const float d1 = d1v[t1];
            const float e0 = a0 + r10 * d1;
            const float e1 = a1 + r11 * d1;
            const float e2 = a2 + r12 * d1;
            const int g1 = b1 + t1 - MAX_R;
            const bool v01 = v0v[t0] && v1v[t1];
            const int base_idx = g0 * (VOX_H * VOX_W) + g1 * VOX_W;
#pragma unroll
            for (int t2 = 0; t2 < 2 * MAX_R + 1; ++t2) {
                const float d2 = d2v[t2];
                const float m0 = si0 * (e0 + r20 * d2);
                const float m1 = si1 * (e1 + r21 * d2);
                const float m2 = si2 * (e2 + r22 * d2);
                const float mahal = m0 * m0 + m1 * m1 + m2 * m2;
                const bool ok = v01 && v2v[t2] && (mahal <= 9.0f);
                if (ok) {
                    const float val = __expf(-0.5f * mahal) * dens;
                    atomicAdd(&volume[base_idx + (b2 + t2 - MAX_R)], val);
                }
            }
        }
    }
}

extern "C" void kernel_launch(void* const* d_in, const int* in_sizes, int n_in,
                              void* d_out, int out_size, void* d_ws, size_t ws_size,
                              hipStream_t stream) {
    const float* positions = (const float*)d_in[0];
    const float* scales    = (const float*)d_in[1];
    const float* rotations = (const float*)d_in[2];
    const float* density   = (const float*)d_in[3];
    float* volume = (float*)d_out;

    const int n = in_sizes[0] / 3;

    // harness poisons d_out with 0xAA before every launch; we need zeros
    hipMemsetAsync(volume, 0, (size_t)out_size * sizeof(float), stream);

    const int block = 256;
    const int grid = (n + block - 1) / block;
    voxelize_splat<<<grid, block, 0, stream>>>(positions, scales, rotations,
                                               density, volume, n);
}

// Round 4
// 99.942 us; speedup vs baseline: 1.0352x; 1.0352x over previous
//
#include <hip/hip_runtime.h>

// Voxelizer: splat N gaussians into a D*H*W f32 volume.
// Round 4: one thread per (point, z-plane) instead of one thread per point.
// R3 counters showed OccupancyPercent=13.45% (391 blocks ~ 1.5/CU), VALUBusy=8%,
// HBM=7% -> latency-bound with a 125-iteration serial loop per thread. 5x the
// threads, 5x shorter chain, ~30 waves/CU.

#define VOX_D 128
#define VOX_H 128
#define VOX_W 128
#define MAX_R 2
#define KW (2 * MAX_R + 1)   // 5

__global__ __launch_bounds__(256) void voxelize_splat(
    const float* __restrict__ positions,  // (N,3)
    const float* __restrict__ scales,     // (N,3)
    const float* __restrict__ rotations,  // (N,4) w,x,y,z
    const float* __restrict__ density,    // (N,)
    float* __restrict__ volume,           // (D*H*W,)
    int n)
{
    const int tid = blockIdx.x * blockDim.x + threadIdx.x;
    if (tid >= n * KW) return;
    const int i  = tid / KW;        // point index
    const int t0 = tid - i * KW;    // which z-plane of the 5^3 stencil [0,4]

    const float p0 = positions[3 * i + 0];
    const float p1 = positions[3 * i + 1];
    const float p2 = positions[3 * i + 2];

    // voxel-space center (all dims are 128)
    const float c0 = (p0 + 1.0f) * 64.0f - 0.5f;
    const float c1 = (p1 + 1.0f) * 64.0f - 0.5f;
    const float c2 = (p2 + 1.0f) * 64.0f - 0.5f;

    // base integer voxel (round half to even, matches jnp.round)
    const int b0 = (int)rintf(c0);
    const int b1 = (int)rintf(c1);
    const int b2 = (int)rintf(c2);

    // this thread's plane; whole plane out of bounds -> done
    const int g0 = b0 + t0 - MAX_R;
    if (g0 < 0 || g0 >= VOX_D) return;

    // quaternion -> rotation matrix (normalized)
    float qw = rotations[4 * i + 0];
    float qx = rotations[4 * i + 1];
    float qy = rotations[4 * i + 2];
    float qz = rotations[4 * i + 3];
    const float qn = rsqrtf(qw * qw + qx * qx + qy * qy + qz * qz);
    qw *= qn; qx *= qn; qy *= qn; qz *= qn;

    const float r00 = 1.0f - 2.0f * (qy * qy + qz * qz);
    const float r01 = 2.0f * (qx * qy - qw * qz);
    const float r02 = 2.0f * (qx * qz + qw * qy);
    const float r10 = 2.0f * (qx * qy + qw * qz);
    const float r11 = 1.0f - 2.0f * (qx * qx + qz * qz);
    const float r12 = 2.0f * (qy * qz - qw * qx);
    const float r20 = 2.0f * (qx * qz - qw * qy);
    const float r21 = 2.0f * (qy * qz + qw * qx);
    const float r22 = 1.0f - 2.0f * (qx * qx + qy * qy);

    const float si0 = 1.0f / (scales[3 * i + 0] + 1e-8f);
    const float si1 = 1.0f / (scales[3 * i + 1] + 1e-8f);
    const float si2 = 1.0f / (scales[3 * i + 2] + 1e-8f);

    const float dens = density[i];
    const float inv_half = 1.0f / 64.0f;

    // fixed plane offset terms: columns of R^T scaled by d0
    const float d0 = ((float)g0 - c0) * inv_half;
    const float a0 = r00 * d0;
    const float a1 = r01 * d0;
    const float a2 = r02 * d0;

    // per-axis normalized offsets and validity for the remaining two axes
    float d1v[KW], d2v[KW];
    bool v1v[KW], v2v[KW];
#pragma unroll
    for (int k = -MAX_R; k <= MAX_R; ++k) {
        const int t = k + MAX_R;
        d1v[t] = ((float)(b1 + k) - c1) * inv_half;
        d2v[t] = ((float)(b2 + k) - c2) * inv_half;
        v1v[t] = (b1 + k >= 0) && (b1 + k < VOX_H);
        v2v[t] = (b2 + k >= 0) && (b2 + k < VOX_W);
    }

    const int plane_base = g0 * (VOX_H * VOX_W);

#pragma unroll
    for (int t1 = 0; t1 < KW; ++t1) {
        const float d1 = d1v[t1];
        const float e0 = a0 + r10 * d1;
        const float e1 = a1 + r11 * d1;
        const float e2 = a2 + r12 * d1;
        const int g1 = b1 + t1 - MAX_R;
        const bool v1 = v1v[t1];
        const int row_base = plane_base + g1 * VOX_W;
#pragma unroll
        for (int t2 = 0; t2 < KW; ++t2) {
            const float d2 = d2v[t2];
            const float m0 = si0 * (e0 + r20 * d2);
            const float m1 = si1 * (e1 + r21 * d2);
            const float m2 = si2 * (e2 + r22 * d2);
            const float mahal = m0 * m0 + m1 * m1 + m2 * m2;
            const bool ok = v1 && v2v[t2] && (mahal <= 9.0f);
            if (ok) {
                const float val = __expf(-0.5f * mahal) * dens;
                atomicAdd(&volume[row_base + (b2 + t2 - MAX_R)], val);
            }
        }
    }
}

extern "C" void kernel_launch(void* const* d_in, const int* in_sizes, int n_in,
                              void* d_out, int out_size, void* d_ws, size_t ws_size,
                              hipStream_t stream) {
    const float* positions = (const float*)d_in[0];
    const float* scales    = (const float*)d_in[1];
    const float* rotations = (const float*)d_in[2];
    const float* density   = (const float*)d_in[3];
    float* volume = (float*)d_out;

    const int n = in_sizes[0] / 3;

    // harness poisons d_out with 0xAA before every launch; we need zeros
    hipMemsetAsync(volume, 0, (size_t)out_size * sizeof(float), stream);

    const int block = 256;
    const int total = n * KW;               // one thread per (point, plane)
    const int grid = (total + block - 1) / block;
    voxelize_splat<<<grid, block, 0, stream>>>(positions, scales, rotations,
                                               density, volume, n);
}

// Round 5
// 98.720 us; speedup vs baseline: 1.0480x; 1.0124x over previous
//
#include <hip/hip_runtime.h>

// Voxelizer: splat N gaussians into a D*H*W f32 volume.
// Round 5: per-point tight AABB pruning. R3/R4 showed runtime scales with
// total site visits (12.5M), not wave count (5x occupancy bought ~9%). The
// mahal<=9 ellipsoid has per-axis half-extent h_a = 3*64*sqrt(sum_j R_aj^2 s_j^2)
// <= 1.92 voxels (s<=0.01), always inside the reference's 5^3 clamp, so
// restricting the loop to ceil/floor of the AABB is exact (pruned sites fail
// mahal<=9 anyway; epsilon guards fp boundary). Typical box 3^3=27 -> ~3M sites.
// Keep the (point, z-plane) split for occupancy.

#define VOX_D 128
#define VOX_H 128
#define VOX_W 128
#define MAX_R 2
#define KW (2 * MAX_R + 1)   // 5

__global__ __launch_bounds__(256) void voxelize_splat(
    const float* __restrict__ positions,  // (N,3)
    const float* __restrict__ scales,     // (N,3)
    const float* __restrict__ rotations,  // (N,4) w,x,y,z
    const float* __restrict__ density,    // (N,)
    float* __restrict__ volume,           // (D*H*W,)
    int n)
{
    const int tid = blockIdx.x * blockDim.x + threadIdx.x;
    if (tid >= n * KW) return;
    const int i  = tid / KW;              // point index
    const int t0 = tid - i * KW - MAX_R;  // this thread's z offset in [-2,2]

    const float p0 = positions[3 * i + 0];
    const float p1 = positions[3 * i + 1];
    const float p2 = positions[3 * i + 2];

    // voxel-space center (all dims are 128)
    const float c0 = (p0 + 1.0f) * 64.0f - 0.5f;
    const float c1 = (p1 + 1.0f) * 64.0f - 0.5f;
    const float c2 = (p2 + 1.0f) * 64.0f - 0.5f;

    // base integer voxel (round half to even, matches jnp.round)
    const int b0 = (int)rintf(c0);
    const int b1 = (int)rintf(c1);
    const int b2 = (int)rintf(c2);

    const int g0 = b0 + t0;               // this thread's plane

    // quaternion -> rotation matrix (normalized)
    float qw = rotations[4 * i + 0];
    float qx = rotations[4 * i + 1];
    float qy = rotations[4 * i + 2];
    float qz = rotations[4 * i + 3];
    const float qn = rsqrtf(qw * qw + qx * qx + qy * qy + qz * qz);
    qw *= qn; qx *= qn; qy *= qn; qz *= qn;

    const float r00 = 1.0f - 2.0f * (qy * qy + qz * qz);
    const float r01 = 2.0f * (qx * qy - qw * qz);
    const float r02 = 2.0f * (qx * qz + qw * qy);
    const float r10 = 2.0f * (qx * qy + qw * qz);
    const float r11 = 1.0f - 2.0f * (qx * qx + qz * qz);
    const float r12 = 2.0f * (qy * qz - qw * qx);
    const float r20 = 2.0f * (qx * qz - qw * qy);
    const float r21 = 2.0f * (qy * qz + qw * qx);
    const float r22 = 1.0f - 2.0f * (qx * qx + qy * qy);

    const float s0 = scales[3 * i + 0];
    const float s1 = scales[3 * i + 1];
    const float s2 = scales[3 * i + 2];

    // AABB half-extents of the mahal<=9 ellipsoid, in voxel units (+eps for fp)
    const float HS = 3.0f * 64.0f;
    const float h0 = HS * sqrtf(r00 * r00 * s0 * s0 + r01 * r01 * s1 * s1 + r02 * r02 * s2 * s2) + 1e-2f;
    const float h1 = HS * sqrtf(r10 * r10 * s0 * s0 + r11 * r11 * s1 * s1 + r12 * r12 * s2 * s2) + 1e-2f;
    const float h2 = HS * sqrtf(r20 * r20 * s0 * s0 + r21 * r21 * s1 * s1 + r22 * r22 * s2 * s2) + 1e-2f;

    // z-plane pruning: in AABB and in volume
    if ((float)g0 < c0 - h0 || (float)g0 > c0 + h0) return;
    if (g0 < 0 || g0 >= VOX_D) return;

    // y/x integer ranges: AABB ∩ [b-2,b+2] ∩ [0,127]
    int lo1 = (int)ceilf(c1 - h1);  if (lo1 < b1 - MAX_R) lo1 = b1 - MAX_R;  if (lo1 < 0) lo1 = 0;
    int hi1 = (int)floorf(c1 + h1); if (hi1 > b1 + MAX_R) hi1 = b1 + MAX_R;  if (hi1 > VOX_H - 1) hi1 = VOX_H - 1;
    int lo2 = (int)ceilf(c2 - h2);  if (lo2 < b2 - MAX_R) lo2 = b2 - MAX_R;  if (lo2 < 0) lo2 = 0;
    int hi2 = (int)floorf(c2 + h2); if (hi2 > b2 + MAX_R) hi2 = b2 + MAX_R;  if (hi2 > VOX_W - 1) hi2 = VOX_W - 1;
    if (lo1 > hi1 || lo2 > hi2) return;

    const float si0 = 1.0f / (s0 + 1e-8f);
    const float si1 = 1.0f / (s1 + 1e-8f);
    const float si2 = 1.0f / (s2 + 1e-8f);
    const float dens = density[i];
    const float inv_half = 1.0f / 64.0f;

    // fixed plane terms: columns of R^T scaled by d0
    const float d0 = ((float)g0 - c0) * inv_half;
    const float a0 = r00 * d0;
    const float a1 = r01 * d0;
    const float a2 = r02 * d0;

    const int plane_base = g0 * (VOX_H * VOX_W);

    for (int g1 = lo1; g1 <= hi1; ++g1) {
        const float d1 = ((float)g1 - c1) * inv_half;
        const float e0 = a0 + r10 * d1;
        const float e1 = a1 + r11 * d1;
        const float e2 = a2 + r12 * d1;
        const int row_base = plane_base + g1 * VOX_W;
        for (int g2 = lo2; g2 <= hi2; ++g2) {
            const float d2 = ((float)g2 - c2) * inv_half;
            const float m0 = si0 * (e0 + r20 * d2);
            const float m1 = si1 * (e1 + r21 * d2);
            const float m2 = si2 * (e2 + r22 * d2);
            const float mahal = m0 * m0 + m1 * m1 + m2 * m2;
            if (mahal <= 9.0f) {
                const float val = __expf(-0.5f * mahal) * dens;
                atomicAdd(&volume[row_base + g2], val);
            }
        }
    }
}

extern "C" void kernel_launch(void* const* d_in, const int* in_sizes, int n_in,
                              void* d_out, int out_size, void* d_ws, size_t ws_size,
                              hipStream_t stream) {
    const float* positions = (const float*)d_in[0];
    const float* scales    = (const float*)d_in[1];
    const float* rotations = (const float*)d_in[2];
    const float* density   = (const float*)d_in[3];
    float* volume = (float*)d_out;

    const int n = in_sizes[0] / 3;

    // harness poisons d_out with 0xAA before every launch; we need zeros
    hipMemsetAsync(volume, 0, (size_t)out_size * sizeof(float), stream);

    const int block = 256;
    const int total = n * KW;               // one thread per (point, plane)
    const int grid = (total + block - 1) / block;
    voxelize_splat<<<grid, block, 0, stream>>>(positions, scales, rotations,
                                               density, volume, n);
}